// Round 6
// baseline (186.089 us; speedup 1.0000x reference)
//
#include <hip/hip_runtime.h>
#include <hip/hip_bf16.h>
#include <math.h>

typedef __attribute__((ext_vector_type(8))) __bf16 bf16x8;
typedef __attribute__((ext_vector_type(4))) float f32x4;
typedef __attribute__((ext_vector_type(16))) float f32x16;
typedef __attribute__((ext_vector_type(4))) unsigned short us4;

#define DEVINL static __device__ __forceinline__

DEVINL unsigned short f2bf(float f) {
  union { float f; unsigned int u; } v; v.f = f;
  return (unsigned short)((v.u + 0x7FFFu + ((v.u >> 16) & 1u)) >> 16);  // RNE
}

DEVINL unsigned short f2bf_hw(float f) {
  __bf16 h = (__bf16)f;
  union { __bf16 h; unsigned short u; } v; v.h = h;
  return v.u;
}

DEVINL unsigned pk2(float a, float b) {
  return (unsigned)f2bf_hw(a) | ((unsigned)f2bf_hw(b) << 16);
}

DEVINL f32x4 mfma16(bf16x8 a, bf16x8 b, f32x4 c) {
  return __builtin_amdgcn_mfma_f32_16x16x32_bf16(a, b, c, 0, 0, 0);
}
DEVINL f32x16 mfma32(bf16x8 a, bf16x8 b, f32x16 c) {
  return __builtin_amdgcn_mfma_f32_32x32x16_bf16(a, b, c, 0, 0, 0);
}

#define GLOAD16(GP, LP)                                                        \
  __builtin_amdgcn_global_load_lds(                                            \
      (const __attribute__((address_space(1))) void*)(GP),                     \
      (__attribute__((address_space(3))) void*)(LP), 16, 0, 0)

// problem constants
static constexpr int kB = 4, kT = 2048, kC = 1024, kH = 16, kD = 64;
static constexpr int kM = kB * kT;  // 8192

// ---------------------------------------------------------------- prep ----
__global__ __launch_bounds__(256) void prep_kernel(
    const float* __restrict__ x, unsigned short* __restrict__ xb,
    const float* __restrict__ Wa, unsigned short* __restrict__ WaT,
    const float* __restrict__ Wp, unsigned short* __restrict__ WpT,
    float* __restrict__ cosT, float* __restrict__ sinT) {
  const int blk = blockIdx.x;
  if (blk < 2048) {
    const int n4 = kM * kC / 4;
    for (int i = blk * 256 + threadIdx.x; i < n4; i += 2048 * 256) {
      float4 v = ((const float4*)x)[i];
      us4 o;
      o[0] = f2bf(v.x); o[1] = f2bf(v.y); o[2] = f2bf(v.z); o[3] = f2bf(v.w);
      ((us4*)xb)[i] = o;
    }
  } else if (blk < 2048 + 3072 + 1024) {
    __shared__ float tile[32][33];
    int t = blk - 2048;
    const float* W; unsigned short* WT; int N, bx, by;
    if (t < 3072) { W = Wa; WT = WaT; N = 3072; bx = t % 96; by = t / 96; }
    else { t -= 3072; W = Wp; WT = WpT; N = 1024; bx = t % 32; by = t / 32; }
    const int n0 = bx * 32, k0 = by * 32;
    const int tx = threadIdx.x & 31, ty = threadIdx.x >> 5;
#pragma unroll
    for (int i = 0; i < 4; ++i)
      tile[ty + i * 8][tx] = W[(size_t)(k0 + ty + i * 8) * N + n0 + tx];
    __syncthreads();
#pragma unroll
    for (int i = 0; i < 4; ++i)
      WT[(size_t)(n0 + ty + i * 8) * 1024 + k0 + tx] = f2bf(tile[tx][ty + i * 8]);
  } else {
    int idx = (blk - 6144) * 256 + threadIdx.x;
    int d2 = idx >> 11, t = idx & 2047;
    double ang = (double)t * pow(10000.0, -(double)d2 / 32.0);
    cosT[idx] = (float)cos(ang);
    sinT[idx] = (float)sin(ang);
  }
}

// ------------------------------------------------------ qkv GEMM (8ph) ----
// Round-6: faithful m201-class 8-phase port for qkv.  256x256 tile, BK=64,
// 8 waves (2M x 4N), per-wave 128x64 output = acc[8][4].  2 LDS dbuf
// (ping=even tiles, pong=odd).  Quadrant phases per K-tile:
//   ph a:(mh0,nh0) b:(mh0,nh1) c:(mh1,nh1) d:(mh1,nh0); 16 MFMA each.
// A-frags (one mh) + BOTH B nh-sets held in regs: reads 12/4/8/0 per tile.
// Staging: one slice per phase (2 gload_lds).  Slice = the rows one
// quadrant-pair reads: A-mh = rows {mh*64..+63} u {128+mh*64..+63};
// B-nh = 4x 32-row groups.  Slice-free schedule (derived, all read/write
// pairs >= 2 barriers apart; deadlines proven against the waits):
//   iter I computes u=2I (ping ph1-4), v=2I+1 (pong ph5-8)
//   ph1: stage v.Bnh0   ph2: v.Amh1    (pong regions last read 2 phases ago)
//   ph3: w.Amh0  ph4: w.Bnh1  ph5: w.Bnh0  ph6: w.Amh1   (w=2I+2 -> ping)
//   ph7: x.Amh0  ph8: x.Bnh1                              (x=2I+3 -> pong)
// Counted waits (T4, never 0 mid-loop): vmcnt(4) at ph4 (allows ph3+ph4
// stages; proves v fully landed) and ph8 (allows ph7+ph8; proves w landed).
// Prologue: tile0 all + tile1.{Amh0,Bnh1}, vmcnt(4).  Granule swizzle
// kb ^= row&7 both-sides (r2-verified conflict-free).  T5 setprio.
// Epilogue: RoPE + scatter (fused, as before).
__global__ __launch_bounds__(512, 2) void qkv_gemm8_kernel(
    const unsigned short* __restrict__ A, const unsigned short* __restrict__ Bt,
    const float* __restrict__ cosT, const float* __restrict__ sinT,
    unsigned short* __restrict__ Qr, unsigned short* __restrict__ Kr,
    unsigned short* __restrict__ Vtg) {
  __shared__ unsigned short As[2][256 * 64];  // 64 KiB
  __shared__ unsigned short Bs[2][256 * 64];  // 64 KiB
  const int tid = threadIdx.x;
  const int wave = tid >> 6, lane = tid & 63;
  const int Kdim = 1024;

  // XCD swizzle, 384 wgs = 8 x 48 (bijective)
  const int lin = blockIdx.y * gridDim.x + blockIdx.x;
  const int wg = (lin & 7) * 48 + (lin >> 3);
  const int n0 = (wg % 12) * 256, m0 = (wg / 12) * 256;

  const int wr = wave >> 2, wc = wave & 3;  // 2M x 4N
  const int fr = lane & 15, ku = lane >> 4, rx = lane & 7;
  const int srow8 = lane >> 3;
  const int sgk = (rx ^ srow8) << 3;  // source k halfword offset (swizzle)

  f32x4 acc[8][4] = {};
  bf16x8 a[4][2], b0[2][2], b1[2][2];

  auto stageA = [&](int t, int mh, int l) {
    const int rb = l * 128 + mh * 64 + wave * 8;
    GLOAD16(A + (size_t)(m0 + rb + srow8) * Kdim + (t << 6) + sgk,
            &As[t & 1][rb * 64]);
  };
  auto stageB = [&](int t, int nh, int l) {
    const int rb = l * 128 + (wave >> 2) * 64 + nh * 32 + (wave & 3) * 8;
    GLOAD16(Bt + (size_t)(n0 + rb + srow8) * Kdim + (t << 6) + sgk,
            &Bs[t & 1][rb * 64]);
  };
  auto readA = [&](int bb, int mh) {
#pragma unroll
    for (int i = 0; i < 4; ++i)
#pragma unroll
      for (int kh = 0; kh < 2; ++kh) {
        const int row = wr * 128 + mh * 64 + i * 16 + fr;
        a[i][kh] = *(const bf16x8*)((const unsigned char*)As[bb] + row * 128 +
                                    ((((kh << 2) | ku) ^ rx) << 4));
      }
  };
  auto readB = [&](int bb, int nh, bf16x8 (&bx)[2][2]) {
#pragma unroll
    for (int j = 0; j < 2; ++j)
#pragma unroll
      for (int kh = 0; kh < 2; ++kh) {
        const int row = wc * 64 + nh * 32 + j * 16 + fr;
        bx[j][kh] = *(const bf16x8*)((const unsigned char*)Bs[bb] + row * 128 +
                                     ((((kh << 2) | ku) ^ rx) << 4));
      }
  };
  auto mm = [&](int mh, bf16x8 (&bx)[2][2], int nh) {
#pragma unroll
    for (int kh = 0; kh < 2; ++kh)
#pragma unroll
      for (int i = 0; i < 4; ++i)
#pragma unroll
        for (int j = 0; j < 2; ++j)
          acc[mh * 4 + i][nh * 2 + j] =
              mfma16(a[i][kh], bx[j][kh], acc[mh * 4 + i][nh * 2 + j]);
  };

#define MIDBAR()                                          \
  __builtin_amdgcn_sched_barrier(0);                      \
  __builtin_amdgcn_s_barrier();                           \
  asm volatile("s_waitcnt lgkmcnt(0)" ::: "memory");      \
  __builtin_amdgcn_sched_barrier(0);                      \
  __builtin_amdgcn_s_setprio(1)
#define ENDBAR()                                          \
  __builtin_amdgcn_s_setprio(0);                          \
  __builtin_amdgcn_s_barrier()

  const int NT = 16, NI = 8;

  // prologue: tile0 (4 slices) + tile1.{Amh0, Bnh1}
  stageA(0, 0, 0); stageA(0, 0, 1);
  stageB(0, 1, 0); stageB(0, 1, 1);
  stageB(0, 0, 0); stageB(0, 0, 1);
  stageA(0, 1, 0); stageA(0, 1, 1);
  stageA(1, 0, 0); stageA(1, 0, 1);
  stageB(1, 1, 0); stageB(1, 1, 1);
  asm volatile("s_waitcnt vmcnt(4)" ::: "memory");
  __builtin_amdgcn_sched_barrier(0);
  __builtin_amdgcn_s_barrier();

  for (int I = 0; I < NI; ++I) {
    const int v = 2 * I + 1, w = 2 * I + 2, x = 2 * I + 3;

    // ---- ph1: (mh0,nh0) of tile u ----
    readA(0, 0); readB(0, 0, b0);
    stageB(v, 0, 0); stageB(v, 0, 1);
    MIDBAR(); mm(0, b0, 0); ENDBAR();
    // ---- ph2: (mh0,nh1) ----
    readB(0, 1, b1);
    stageA(v, 1, 0); stageA(v, 1, 1);
    MIDBAR(); mm(0, b1, 1); ENDBAR();
    // ---- ph3: (mh1,nh1) ----
    readA(0, 1);
    if (w < NT) { stageA(w, 0, 0); stageA(w, 0, 1); }
    MIDBAR(); mm(1, b1, 1); ENDBAR();
    // ---- ph4: (mh1,nh0), wait: v fully landed ----
    if (w < NT) {
      stageB(w, 1, 0); stageB(w, 1, 1);
      asm volatile("s_waitcnt vmcnt(4)" ::: "memory");
    } else {
      asm volatile("s_waitcnt vmcnt(0)" ::: "memory");
    }
    MIDBAR(); mm(1, b0, 0); ENDBAR();

    // ---- ph5: (mh0,nh0) of tile v ----
    readA(1, 0); readB(1, 0, b0);
    if (w < NT) { stageB(w, 0, 0); stageB(w, 0, 1); }
    MIDBAR(); mm(0, b0, 0); ENDBAR();
    // ---- ph6: (mh0,nh1) ----
    readB(1, 1, b1);
    if (w < NT) { stageA(w, 1, 0); stageA(w, 1, 1); }
    MIDBAR(); mm(0, b1, 1); ENDBAR();
    // ---- ph7: (mh1,nh1) ----
    readA(1, 1);
    if (x < NT) { stageA(x, 0, 0); stageA(x, 0, 1); }
    MIDBAR(); mm(1, b1, 1); ENDBAR();
    // ---- ph8: (mh1,nh0), wait: w fully landed ----
    if (x < NT) {
      stageB(x, 1, 0); stageB(x, 1, 1);
      asm volatile("s_waitcnt vmcnt(4)" ::: "memory");
    }
    MIDBAR(); mm(1, b0, 0); ENDBAR();
  }
#undef MIDBAR
#undef ENDBAR

  // epilogue: RoPE + scatter.  C layout col = lane&15, row = (lane>>4)*4+r
  const int lr = (lane >> 4) * 4;
  const int fc = lane & 15;
#pragma unroll
  for (int i = 0; i < 8; ++i) {
    int mb = m0 + wr * 128 + i * 16 + lr;
    int b = mb >> 11, t0 = mb & 2047;
#pragma unroll
    for (int j = 0; j < 4; ++j) {
      int n = n0 + wc * 64 + j * 16 + fc;
      int sec = n >> 10;
      int c = n & 1023;
      int h = c >> 6, d = c & 63;
      size_t bh = (size_t)(b * 16 + h);
      if (sec == 2) {
        us4 pk;
#pragma unroll
        for (int r = 0; r < 4; ++r) pk[r] = f2bf(acc[i][j][r]);
        *(us4*)&Vtg[(bh * 64 + d) * 2048 + t0] = pk;
      } else {
        unsigned short* dst = (sec == 0) ? Qr : Kr;
        float4 c4 = *(const float4*)&cosT[(d >> 1) * 2048 + t0];
        float4 s4 = *(const float4*)&sinT[(d >> 1) * 2048 + t0];
        const float* cp = (const float*)&c4;
        const float* sp = (const float*)&s4;
#pragma unroll
        for (int r = 0; r < 4; ++r) {
          float vv = acc[i][j][r];
          float pv = __shfl_xor(vv, 1);
          float y = (d & 1) ? fmaf(pv, sp[r], vv * cp[r])
                            : fmaf(vv, cp[r], -pv * sp[r]);
          dst[(bh * 2048 + t0 + r) * 64 + d] = f2bf(y);
        }
      }
    }
  }
}

// ------------------------------------------------------- proj GEMM ----
// (frozen r3 structure: 256x128, BK=64, 8 waves, ring-3, granule swizzle)
template <int EPI>
__global__ __launch_bounds__(512, 2) void gemm_bt_kernel(
    const unsigned short* __restrict__ A, const unsigned short* __restrict__ Bt,
    float* __restrict__ Cout, int Ndim, int Kdim) {
  __shared__ unsigned short As[3][256 * 64];
  __shared__ unsigned short Bs[3][128 * 64];
  const int tid = threadIdx.x;
  const int wave = tid >> 6, lane = tid & 63;

  const int nwg = gridDim.x * gridDim.y;
  const int lin = blockIdx.y * gridDim.x + blockIdx.x;
  const int wg = (lin & 7) * (nwg >> 3) + (lin >> 3);
  const int n0 = (wg % gridDim.x) * 128, m0 = (wg / gridDim.x) * 256;

  const int wr = wave >> 1, wc = wave & 1;

  f32x4 acc[4][4] = {};

  const int fr = lane & 15;
  const int sblk = tid;
  const int srow3 = sblk >> 3, skb = sblk & 7;
  const int sgran = (skb ^ (srow3 & 7)) << 3;

  auto stageA = [&](int t, int l) {
    const int bb = t % 3;
    const int k0 = t << 6;
    const int row = (l << 6) + srow3;
    GLOAD16(A + (size_t)(m0 + row) * Kdim + k0 + sgran,
            &As[bb][(l * 512 + wave * 64) * 8]);
  };
  auto stageB = [&](int t, int l) {
    const int bb = t % 3;
    const int k0 = t << 6;
    const int row = (l << 6) + srow3;
    GLOAD16(Bt + (size_t)(n0 + row) * Kdim + k0 + sgran,
            &Bs[bb][(l * 512 + wave * 64) * 8]);
  };

  const int NT = Kdim >> 6;

  stageA(0, 0); stageA(0, 1); stageA(0, 2); stageA(0, 3);
  stageB(0, 0); stageB(0, 1);
  stageA(1, 0); stageA(1, 1); stageA(1, 2); stageA(1, 3);
  stageB(1, 0); stageB(1, 1);
  asm volatile("s_waitcnt vmcnt(6)" ::: "memory");
  __builtin_amdgcn_sched_barrier(0);
  __builtin_amdgcn_s_barrier();

  const int rx = lane & 7, ku = lane >> 4;

  for (int t = 0; t < NT; ++t) {
    const int buf = t % 3;
    const unsigned char* Ab = (const unsigned char*)As[buf];
    const unsigned char* Bb = (const unsigned char*)Bs[buf];
    bf16x8 af[4], bfr[4];

    {
      const int col = ((ku ^ rx) << 4);
#pragma unroll
      for (int f = 0; f < 4; ++f)
        af[f] = *(const bf16x8*)(Ab + (wr * 64 + f * 16 + fr) * 128 + col);
#pragma unroll
      for (int f = 0; f < 4; ++f)
        bfr[f] = *(const bf16x8*)(Bb + (wc * 64 + f * 16 + fr) * 128 + col);
    }
    if (t + 2 < NT) { stageA(t + 2, 0); stageA(t + 2, 1); stageB(t + 2, 0); }
    __builtin_amdgcn_s_barrier();
    asm volatile("s_waitcnt lgkmcnt(0)" ::: "memory");
    __builtin_amdgcn_sched_barrier(0);
    __builtin_amdgcn_s_setprio(1);
#pragma unroll
    for (int i = 0; i < 4; ++i)
#pragma unroll
      for (int j = 0; j < 4; ++j)
        acc[i][j] = mfma16(af[i], bfr[j], acc[i][j]);
    __builtin_amdgcn_s_setprio(0);
    __builtin_amdgcn_s_barrier();

    {
      const int col = (((4 | ku) ^ rx) << 4);
#pragma unroll
      for (int f = 0; f < 4; ++f)
        af[f] = *(const bf16x8*)(Ab + (wr * 64 + f * 16 + fr) * 128 + col);
#pragma unroll
      for (int f = 0; f < 4; ++f)
        bfr[f] = *(const bf16x8*)(Bb + (wc * 64 + f * 16 + fr) * 128 + col);
    }
    if (t + 2 < NT) { stageA(t + 2, 2); stageA(t + 2, 3); stageB(t + 2, 1); }
    if (t + 2 < NT) {
      asm volatile("s_waitcnt vmcnt(6)" ::: "memory");
    } else if (t + 1 < NT) {
      asm volatile("s_waitcnt vmcnt(0)" ::: "memory");
    }
    __builtin_amdgcn_sched_barrier(0);
    __builtin_amdgcn_s_barrier();
    asm volatile("s_waitcnt lgkmcnt(0)" ::: "memory");
    __builtin_amdgcn_sched_barrier(0);
    __builtin_amdgcn_s_setprio(1);
#pragma unroll
    for (int i = 0; i < 4; ++i)
#pragma unroll
      for (int j = 0; j < 4; ++j)
        acc[i][j] = mfma16(af[i], bfr[j], acc[i][j]);
    __builtin_amdgcn_s_setprio(0);
    __builtin_amdgcn_s_barrier();
  }

  const int lr = (lane >> 4) * 4;
  const int fc = lane & 15;
#pragma unroll
  for (int i = 0; i < 4; ++i) {
    int mb = m0 + wr * 64 + i * 16 + lr;
#pragma unroll
    for (int j = 0; j < 4; ++j) {
      int n = n0 + wc * 64 + j * 16 + fc;
#pragma unroll
      for (int r = 0; r < 4; ++r)
        Cout[(size_t)(mb + r) * Ndim + n] = acc[i][j][r];
    }
  }
}

// ----------------------------------------------------------- attention ----
// (r5 structure: 2-wave blocks, balanced (c,31-c) pairing, 1024 wgs)
__global__ __launch_bounds__(128, 2)
void attn_kernel(const unsigned short* __restrict__ Qr,
                 const unsigned short* __restrict__ Kr,
                 const unsigned short* __restrict__ Vtg,
                 unsigned short* __restrict__ Yb) {
  __shared__ unsigned short Ks[2][64 * 64];
  __shared__ unsigned short Vs[2][64 * 64];

  const int tid = threadIdx.x;
  const int wave = tid >> 6, lane = tid & 63;
  const int q31 = lane & 31, hi = lane >> 5;
  const int srow = lane >> 3;
  const int sblk = (lane & 7) ^ srow;
  const int rswz = (lane & 7) << 4;

  int lin = blockIdx.y * 8 + blockIdx.x;
  int wg = (lin & 7) * 128 + (lin >> 3);
  const int cpair = wg & 15;
  const int bh = wg >> 4;

  const unsigned short* Qg = Qr + (size_t)bh * 2048 * 64;
  const unsigned short* Kg = Kr + (size_t)bh * 2048 * 64;
  const unsigned short* Vg = Vtg + (size_t)bh * 64 * 2048;

  const float c = 0.18033688f;
  const float THR = 44.0f;

  auto stage = [&](int j, int bb) {
    int kv0s = j * 64;
#pragma unroll
    for (int o = 0; o < 4; ++o) {
      int s = o * 2 + wave;
      int row = s * 8 + srow;
      GLOAD16(Kg + ((size_t)(kv0s + row) * 64 + sblk * 8), &Ks[bb][s * 512]);
      GLOAD16(Vg + ((size_t)row * 2048 + kv0s + sblk * 8), &Vs[bb][s * 512]);
    }
  };

  for (int seg = 0; seg < 2; ++seg) {
    const int qb = seg ? (31 - cpair) : cpair;
    const int qw = qb * 64 + wave * 32;
    const int qg = qw + q31;
    const int NT = qb + 1;

    bf16x8 qf[4];
#pragma unroll
    for (int ds = 0; ds < 4; ++ds)
      qf[ds] = *(const bf16x8*)&Qg[(size_t)qg * 64 + ds * 16 + hi * 8];

    float mrow = -1e30f, lrow = 0.f;
    f32x16 y0 = {}, y1 = {};

    stage(0, 0);
    asm volatile("s_waitcnt vmcnt(0)" ::: "memory");
    __syncthreads();

    for (int t = 0; t < NT; ++t) {
      const int buf = t & 1;
      if (t + 1 < NT) stage(t + 1, buf ^ 1);
      const int kv0 = t * 64;

      if (kv0 <= qw + 31) {
        f32x16 st[2] = {};
        __builtin_amdgcn_s_setprio(1);
#pragma unroll
        for (int sub = 0; sub < 2; ++sub) {
          const unsigned char* kbase =
              (const unsigned char*)Ks[buf] + (sub * 32 + q31) * 128;
#pragma unroll
          for (int ds = 0; ds < 4; ++ds) {
            bf16x8 af = *(const bf16x8*)(kbase + ((ds * 32 + hi * 16) ^ rswz));
            st[sub] = mfma32(af, qf[ds], st[sub]);
          }
        }
        __builtin_amdgcn_s_setprio(0);

        if (kv0 + 63 > qw) {
#pragma unroll
          for (int sub = 0; sub < 2; ++sub)
#pragma unroll
            for (int r = 0; r < 16; ++r) {
              int kv = kv0 + sub * 32 + (r & 3) + 8 * (r >> 2) + 4 * hi;
              if (kv > qg) st[sub][r] = -1e30f;
            }
        }

        float tm = st[0][0];
#pragma unroll
        for (int r = 1; r < 16; ++r) tm = fmaxf(tm, st[0][r]);
#pragma unroll
        for (int r = 0; r < 16; ++r) tm = fmaxf(tm, st[1][r]);
        tm = fmaxf(tm, __shfl_xor(tm, 32));

        if (!__all(tm <= mrow + THR)) {
          float mn = fmaxf(mrow, tm);
          float al = __builtin_amdgcn_exp2f((mrow - mn) * c);
          mrow = mn;
          lrow *= al;
#pragma unroll
          for (int r = 0; r < 16; ++r) { y0[r] *= al; y1[r] *= al; }
        }

        const float mc = mrow * c;
        float ps = 0.f;
        unsigned pkw[2][8];
#pragma unroll
        for (int sub = 0; sub < 2; ++sub)
#pragma unroll
          for (int j = 0; j < 8; ++j) {
            float pa = __builtin_amdgcn_exp2f(fmaf(st[sub][2 * j], c, -mc));
            float pb = __builtin_amdgcn_exp2f(fmaf(st[sub][2 * j + 1], c, -mc));
            ps += pa + pb;
            pkw[sub][j] = pk2(pa, pb);
          }
        ps += __shfl_xor(ps, 32);
        lrow += ps;

        __builtin_amdgcn_s_setprio(1);
#pragma unroll
        for (int sub = 0; sub < 2; ++sub) {
#pragma unroll
          for (int ksl = 0; ksl < 2; ++ksl) {
            unsigned w0 = pkw[sub][ksl * 4 + 0], w2 = pkw[sub][ksl * 4 + 2];
            unsigned w1 = pkw[sub][ksl * 4 + 1], w3 = pkw[sub][ksl * 4 + 3];
            asm volatile("v_permlane32_swap_b32 %0, %1" : "+v"(w0), "+v"(w2));
            asm volatile("v_permlane32_swap_b32 %0, %1" : "+v"(w1), "+v"(w3));
            union { bf16x8 v; unsigned u[4]; } pf;
            pf.u[0] = w0; pf.u[1] = w1; pf.u[2] = w2; pf.u[3] = w3;
            const int cb = sub * 64 + ksl * 32 + hi * 16;
#pragma unroll
            for (int dm = 0; dm < 2; ++dm) {
              const int row = dm * 32 + q31;
              bf16x8 vf = *(const bf16x8*)((const unsigned char*)Vs[buf] +
                                           row * 128 + (cb ^ rswz));
              if (dm == 0) y0 = mfma32(vf, pf.v, y0);
              else         y1 = mfma32(vf, pf.v, y1);
            }
          }
        }
        __builtin_amdgcn_s_setprio(0);
      }

      __syncthreads();
    }

    const int b = bh >> 4, h = bh & 15;
    float inv = __builtin_amdgcn_rcpf(lrow);
    unsigned short* yrow = Yb + (size_t)(b * 2048 + qg) * 1024 + h * 64;
#pragma unroll
    for (int dm = 0; dm < 2; ++dm)
#pragma unroll
      for (int g = 0; g < 4; ++g) {
        us4 o;
#pragma unroll
        for (int e = 0; e < 4; ++e) {
          float yv = dm ? y1[g * 4 + e] : y0[g * 4 + e];
          o[e] = f2bf_hw(yv * inv);
        }
        *(us4*)&yrow[dm * 32 + g * 8 + hi * 4] = o;
      }
  }
}

// ---------------------------------------------------------------- launch ----
extern "C" void kernel_launch(void* const* d_in, const int* in_sizes, int n_in,
                              void* d_out, int out_size, void* d_ws,
                              size_t ws_size, hipStream_t stream) {
  const float* x = (const float*)d_in[0];
  const float* Wa = (const float*)d_in[1];
  const float* Wp = (const float*)d_in[2];
  float* out = (float*)d_out;
  char* ws = (char*)d_ws;

  constexpr size_t OFF_WAT = 0;
  constexpr size_t OFF_WPT = 6291456;
  constexpr size_t OFF_COS = 8388608;
  constexpr size_t OFF_SIN = 8650752;
  constexpr size_t OFF_XB  = 8912896;
  constexpr size_t OFF_Q   = 25690112;
  constexpr size_t OFF_K   = 42467328;
  constexpr size_t OFF_V   = 59244544;

  unsigned short* WaT = (unsigned short*)(ws + OFF_WAT);
  unsigned short* WpT = (unsigned short*)(ws + OFF_WPT);
  float* cosT = (float*)(ws + OFF_COS);
  float* sinT = (float*)(ws + OFF_SIN);
  unsigned short* xb = (unsigned short*)(ws + OFF_XB);
  unsigned short* Yb = xb;
  unsigned short* Qr = (unsigned short*)(ws + OFF_Q);
  unsigned short* Kr = (unsigned short*)(ws + OFF_K);
  unsigned short* Vt = (unsigned short*)(ws + OFF_V);

  // 1) prep (merged)
  prep_kernel<<<2048 + 3072 + 1024 + 256, 256, 0, stream>>>(
      x, xb, Wa, WaT, Wp, WpT, cosT, sinT);

  // 2) qkv = x @ W_attn, 8-phase 256^2 + fused RoPE/scatter (384 wgs)
  qkv_gemm8_kernel<<<dim3(12, 32), 512, 0, stream>>>(
      xb, WaT, cosT, sinT, Qr, Kr, Vt);

  // 3) causal flash attention -> Yb (B,T,C) bf16
  attn_kernel<<<dim3(8, 128), 128, 0, stream>>>(Qr, Kr, Vt, Yb);

  // 4) out = y @ W_proj (frozen r3 GEMM; 256 wgs = 1.0/CU)
  gemm_bt_kernel<0><<<dim3(8, 32), 512, 0, stream>>>(
      Yb, WpT, out, 1024, 1024);
}

// Round 7
// 176.922 us; speedup vs baseline: 1.0518x; 1.0518x over previous
//
#include <hip/hip_runtime.h>
#include <hip/hip_bf16.h>
#include <math.h>

typedef __attribute__((ext_vector_type(8))) __bf16 bf16x8;
typedef __attribute__((ext_vector_type(4))) float f32x4;
typedef __attribute__((ext_vector_type(16))) float f32x16;
typedef __attribute__((ext_vector_type(4))) unsigned short us4;

#define DEVINL static __device__ __forceinline__

DEVINL unsigned short f2bf(float f) {
  union { float f; unsigned int u; } v; v.f = f;
  return (unsigned short)((v.u + 0x7FFFu + ((v.u >> 16) & 1u)) >> 16);  // RNE
}

DEVINL unsigned short f2bf_hw(float f) {
  __bf16 h = (__bf16)f;
  union { __bf16 h; unsigned short u; } v; v.h = h;
  return v.u;
}

DEVINL unsigned pk2(float a, float b) {
  return (unsigned)f2bf_hw(a) | ((unsigned)f2bf_hw(b) << 16);
}

DEVINL f32x4 mfma16(bf16x8 a, bf16x8 b, f32x4 c) {
  return __builtin_amdgcn_mfma_f32_16x16x32_bf16(a, b, c, 0, 0, 0);
}
DEVINL f32x16 mfma32(bf16x8 a, bf16x8 b, f32x16 c) {
  return __builtin_amdgcn_mfma_f32_32x32x16_bf16(a, b, c, 0, 0, 0);
}

#define GLOAD16(GP, LP)                                                        \
  __builtin_amdgcn_global_load_lds(                                            \
      (const __attribute__((address_space(1))) void*)(GP),                     \
      (__attribute__((address_space(3))) void*)(LP), 16, 0, 0)

// problem constants
static constexpr int kB = 4, kT = 2048, kC = 1024, kH = 16, kD = 64;
static constexpr int kM = kB * kT;  // 8192

// ---------------------------------------------------------------- prep ----
__global__ __launch_bounds__(256) void prep_kernel(
    const float* __restrict__ x, unsigned short* __restrict__ xb,
    const float* __restrict__ Wa, unsigned short* __restrict__ WaT,
    const float* __restrict__ Wp, unsigned short* __restrict__ WpT,
    float* __restrict__ cosT, float* __restrict__ sinT) {
  const int blk = blockIdx.x;
  if (blk < 2048) {
    const int n4 = kM * kC / 4;
    for (int i = blk * 256 + threadIdx.x; i < n4; i += 2048 * 256) {
      float4 v = ((const float4*)x)[i];
      us4 o;
      o[0] = f2bf(v.x); o[1] = f2bf(v.y); o[2] = f2bf(v.z); o[3] = f2bf(v.w);
      ((us4*)xb)[i] = o;
    }
  } else if (blk < 2048 + 3072 + 1024) {
    __shared__ float tile[32][33];
    int t = blk - 2048;
    const float* W; unsigned short* WT; int N, bx, by;
    if (t < 3072) { W = Wa; WT = WaT; N = 3072; bx = t % 96; by = t / 96; }
    else { t -= 3072; W = Wp; WT = WpT; N = 1024; bx = t % 32; by = t / 32; }
    const int n0 = bx * 32, k0 = by * 32;
    const int tx = threadIdx.x & 31, ty = threadIdx.x >> 5;
#pragma unroll
    for (int i = 0; i < 4; ++i)
      tile[ty + i * 8][tx] = W[(size_t)(k0 + ty + i * 8) * N + n0 + tx];
    __syncthreads();
#pragma unroll
    for (int i = 0; i < 4; ++i)
      WT[(size_t)(n0 + ty + i * 8) * 1024 + k0 + tx] = f2bf(tile[tx][ty + i * 8]);
  } else {
    int idx = (blk - 6144) * 256 + threadIdx.x;
    int d2 = idx >> 11, t = idx & 2047;
    double ang = (double)t * pow(10000.0, -(double)d2 / 32.0);
    cosT[idx] = (float)cos(ang);
    sinT[idx] = (float)sin(ang);
  }
}

// ---------------------------------------------------------------- GEMM ----
// FROZEN (r3 structure, best measured: qkv 79.6 us).  Five schedule
// variants (128^2 2-bar, 256^2 8ph@1blk, 256x128 2ph, quadrant-8ph) all
// land 79.4-89.2 us at this shape -> schedule-invariant ~640 TF plateau.
// EPI==0: f32 to Cout.  EPI==1: RoPE + scatter Q,K->(B,H,T,D), V->(B,H,D,T).
template <int EPI>
__global__ __launch_bounds__(512, 2) void gemm_bt_kernel(
    const unsigned short* __restrict__ A, const unsigned short* __restrict__ Bt,
    float* __restrict__ Cout, int Ndim, int Kdim,
    const float* __restrict__ cosT, const float* __restrict__ sinT,
    unsigned short* __restrict__ Qr, unsigned short* __restrict__ Kr,
    unsigned short* __restrict__ Vtg) {
  __shared__ unsigned short As[3][256 * 64];  // 96 KiB
  __shared__ unsigned short Bs[3][128 * 64];  // 48 KiB
  const int tid = threadIdx.x;
  const int wave = tid >> 6, lane = tid & 63;

  const int nwg = gridDim.x * gridDim.y;
  const int lin = blockIdx.y * gridDim.x + blockIdx.x;
  const int wg = (lin & 7) * (nwg >> 3) + (lin >> 3);
  const int n0 = (wg % gridDim.x) * 128, m0 = (wg / gridDim.x) * 256;

  const int wr = wave >> 1, wc = wave & 1;

  f32x4 acc[4][4] = {};

  const int fr = lane & 15;
  const int sblk = tid;
  const int srow3 = sblk >> 3, skb = sblk & 7;
  const int sgran = (skb ^ (srow3 & 7)) << 3;

  auto stageA = [&](int t, int l) {
    const int bb = t % 3;
    const int k0 = t << 6;
    const int row = (l << 6) + srow3;
    GLOAD16(A + (size_t)(m0 + row) * Kdim + k0 + sgran,
            &As[bb][(l * 512 + wave * 64) * 8]);
  };
  auto stageB = [&](int t, int l) {
    const int bb = t % 3;
    const int k0 = t << 6;
    const int row = (l << 6) + srow3;
    GLOAD16(Bt + (size_t)(n0 + row) * Kdim + k0 + sgran,
            &Bs[bb][(l * 512 + wave * 64) * 8]);
  };

  const int NT = Kdim >> 6;

  stageA(0, 0); stageA(0, 1); stageA(0, 2); stageA(0, 3);
  stageB(0, 0); stageB(0, 1);
  stageA(1, 0); stageA(1, 1); stageA(1, 2); stageA(1, 3);
  stageB(1, 0); stageB(1, 1);
  asm volatile("s_waitcnt vmcnt(6)" ::: "memory");
  __builtin_amdgcn_sched_barrier(0);
  __builtin_amdgcn_s_barrier();

  const int rx = lane & 7, ku = lane >> 4;

  for (int t = 0; t < NT; ++t) {
    const int buf = t % 3;
    const unsigned char* Ab = (const unsigned char*)As[buf];
    const unsigned char* Bb = (const unsigned char*)Bs[buf];
    bf16x8 af[4], bfr[4];

    {
      const int col = ((ku ^ rx) << 4);
#pragma unroll
      for (int f = 0; f < 4; ++f)
        af[f] = *(const bf16x8*)(Ab + (wr * 64 + f * 16 + fr) * 128 + col);
#pragma unroll
      for (int f = 0; f < 4; ++f)
        bfr[f] = *(const bf16x8*)(Bb + (wc * 64 + f * 16 + fr) * 128 + col);
    }
    if (t + 2 < NT) { stageA(t + 2, 0); stageA(t + 2, 1); stageB(t + 2, 0); }
    __builtin_amdgcn_s_barrier();
    asm volatile("s_waitcnt lgkmcnt(0)" ::: "memory");
    __builtin_amdgcn_sched_barrier(0);
    __builtin_amdgcn_s_setprio(1);
#pragma unroll
    for (int i = 0; i < 4; ++i)
#pragma unroll
      for (int j = 0; j < 4; ++j)
        acc[i][j] = mfma16(af[i], bfr[j], acc[i][j]);
    __builtin_amdgcn_s_setprio(0);
    __builtin_amdgcn_s_barrier();

    {
      const int col = (((4 | ku) ^ rx) << 4);
#pragma unroll
      for (int f = 0; f < 4; ++f)
        af[f] = *(const bf16x8*)(Ab + (wr * 64 + f * 16 + fr) * 128 + col);
#pragma unroll
      for (int f = 0; f < 4; ++f)
        bfr[f] = *(const bf16x8*)(Bb + (wc * 64 + f * 16 + fr) * 128 + col);
    }
    if (t + 2 < NT) { stageA(t + 2, 2); stageA(t + 2, 3); stageB(t + 2, 1); }
    if (t + 2 < NT) {
      asm volatile("s_waitcnt vmcnt(6)" ::: "memory");
    } else if (t + 1 < NT) {
      asm volatile("s_waitcnt vmcnt(0)" ::: "memory");
    }
    __builtin_amdgcn_sched_barrier(0);
    __builtin_amdgcn_s_barrier();
    asm volatile("s_waitcnt lgkmcnt(0)" ::: "memory");
    __builtin_amdgcn_sched_barrier(0);
    __builtin_amdgcn_s_setprio(1);
#pragma unroll
    for (int i = 0; i < 4; ++i)
#pragma unroll
      for (int j = 0; j < 4; ++j)
        acc[i][j] = mfma16(af[i], bfr[j], acc[i][j]);
    __builtin_amdgcn_s_setprio(0);
    __builtin_amdgcn_s_barrier();
  }

  const int lr = (lane >> 4) * 4;
  const int fc = lane & 15;
  if (EPI == 0) {
#pragma unroll
    for (int i = 0; i < 4; ++i) {
      int mb = m0 + wr * 64 + i * 16 + lr;
#pragma unroll
      for (int j = 0; j < 4; ++j) {
        int n = n0 + wc * 64 + j * 16 + fc;
#pragma unroll
        for (int r = 0; r < 4; ++r)
          Cout[(size_t)(mb + r) * Ndim + n] = acc[i][j][r];
      }
    }
  } else {
#pragma unroll
    for (int i = 0; i < 4; ++i) {
      int mb = m0 + wr * 64 + i * 16 + lr;
      int b = mb >> 11, t0 = mb & 2047;
#pragma unroll
      for (int j = 0; j < 4; ++j) {
        int n = n0 + wc * 64 + j * 16 + fc;
        int sec = n >> 10;
        int c = n & 1023;
        int h = c >> 6, d = c & 63;
        size_t bh = (size_t)(b * 16 + h);
        if (sec == 2) {
          us4 pk;
#pragma unroll
          for (int r = 0; r < 4; ++r) pk[r] = f2bf(acc[i][j][r]);
          *(us4*)&Vtg[(bh * 64 + d) * 2048 + t0] = pk;
        } else {
          unsigned short* dst = (sec == 0) ? Qr : Kr;
          float4 c4 = *(const float4*)&cosT[(d >> 1) * 2048 + t0];
          float4 s4 = *(const float4*)&sinT[(d >> 1) * 2048 + t0];
          const float* cp = (const float*)&c4;
          const float* sp = (const float*)&s4;
#pragma unroll
          for (int r = 0; r < 4; ++r) {
            float v = acc[i][j][r];
            float pv = __shfl_xor(v, 1);
            float y = (d & 1) ? fmaf(pv, sp[r], v * cp[r])
                              : fmaf(v, cp[r], -pv * sp[r]);
            dst[(bh * 2048 + t0 + r) * 64 + d] = f2bf(y);
          }
        }
      }
    }
  }
}

// ----------------------------------------------------------- attention ----
// Round-7: T4 pipeline for attn.  Old structure ended every tile with
// __syncthreads() = full vmcnt(0) drain of loads issued only one
// compute-phase earlier (the m218 anti-pattern).  New: ring-3 K/V LDS
// (48 KiB), staging 2 tiles ahead, counted vmcnt(4) + raw s_barrier --
// tile t's wait covers loads issued a FULL tile earlier; never a mid-loop
// drain.  Slot safety (paper-verified): stage(t+2) overwrites the slot
// last read at t-1, separated by end-of-(t-1) barrier + lgkmcnt(0);
// reads of tile t covered by each wave's vmcnt(4) at end of t-1 + barrier.
// Back to 4-wave blocks, balanced (qpair,15-qpair) pairing (34 tiles/wg,
// 512 wgs); 48 KiB -> 3 blocks/CU = 12 waves/CU = 3 waves/SIMD (up from
// r5's 2/SIMD).  Compute core unchanged (swapped-QK^T in-reg softmax, T12
// cvt_pk+permlane, T13 defer-max, T5 setprio, XOR-swizzled staging).
__global__ __launch_bounds__(256, 3)
void attn_kernel(const unsigned short* __restrict__ Qr,
                 const unsigned short* __restrict__ Kr,
                 const unsigned short* __restrict__ Vtg,
                 unsigned short* __restrict__ Yb) {
  __shared__ unsigned short Ks[3][64 * 64];
  __shared__ unsigned short Vs[3][64 * 64];

  const int tid = threadIdx.x;
  const int wave = tid >> 6, lane = tid & 63;
  const int q31 = lane & 31, hi = lane >> 5;
  const int srow = lane >> 3;            // staging: row within 8-row segment
  const int sblk = (lane & 7) ^ srow;    // pre-swizzled source 16B block
  const int rswz = (lane & 7) << 4;      // read-side XOR

  // XCD swizzle (bijective: 512 wgs % 8 == 0)
  int lin = blockIdx.y * 8 + blockIdx.x;
  int wg = (lin & 7) * 64 + (lin >> 3);
  const int qpair = wg & 7;
  const int bh = wg >> 3;

  const unsigned short* Qg = Qr + (size_t)bh * 2048 * 64;
  const unsigned short* Kg = Kr + (size_t)bh * 2048 * 64;
  const unsigned short* Vg = Vtg + (size_t)bh * 64 * 2048;

  const float c = 0.18033688f;   // (1/sqrt(64)) * log2(e)
  const float THR = 44.0f;       // defer-max threshold

  // 4 waves cover 8 K-segs + 8 V-segs: 2 K + 2 V loads per wave (vmcnt 4)
  auto stage = [&](int j, int bb) {
    int kv0s = j * 64;
#pragma unroll
    for (int o = 0; o < 2; ++o) {
      int s = o * 4 + wave;
      int row = s * 8 + srow;
      GLOAD16(Kg + ((size_t)(kv0s + row) * 64 + sblk * 8), &Ks[bb][s * 512]);
      GLOAD16(Vg + ((size_t)row * 2048 + kv0s + sblk * 8), &Vs[bb][s * 512]);
    }
  };

  for (int seg = 0; seg < 2; ++seg) {
    const int qblk = seg ? (15 - qpair) : qpair;
    const int qw = qblk * 128 + wave * 32;
    const int qg = qw + q31;
    const int NT = 2 * qblk + 2;   // >= 2 always

    bf16x8 qf[4];
#pragma unroll
    for (int ds = 0; ds < 4; ++ds)
      qf[ds] = *(const bf16x8*)&Qg[(size_t)qg * 64 + ds * 16 + hi * 8];

    float mrow = -1e30f, lrow = 0.f;
    f32x16 y0 = {}, y1 = {};

    // prologue: tiles 0,1 in flight; wait tile 0 (4 newer = tile 1)
    stage(0, 0);
    stage(1, 1);
    asm volatile("s_waitcnt vmcnt(4)" ::: "memory");
    __builtin_amdgcn_sched_barrier(0);
    __builtin_amdgcn_s_barrier();

    for (int t = 0; t < NT; ++t) {
      const int buf = t % 3;
      if (t + 2 < NT) stage(t + 2, (t + 2) % 3);
      __builtin_amdgcn_sched_barrier(0);
      const int kv0 = t * 64;

      if (kv0 <= qw + 31) {  // skip fully-masked wave-tiles
        f32x16 st[2] = {};
        __builtin_amdgcn_s_setprio(1);
#pragma unroll
        for (int sub = 0; sub < 2; ++sub) {
          const unsigned char* kbase =
              (const unsigned char*)Ks[buf] + (sub * 32 + q31) * 128;
#pragma unroll
          for (int ds = 0; ds < 4; ++ds) {
            bf16x8 af = *(const bf16x8*)(kbase + ((ds * 32 + hi * 16) ^ rswz));
            st[sub] = mfma32(af, qf[ds], st[sub]);
          }
        }
        __builtin_amdgcn_s_setprio(0);

        if (kv0 + 63 > qw) {  // causal mask, diag-crossing tiles only
#pragma unroll
          for (int sub = 0; sub < 2; ++sub)
#pragma unroll
            for (int r = 0; r < 16; ++r) {
              int kv = kv0 + sub * 32 + (r & 3) + 8 * (r >> 2) + 4 * hi;
              if (kv > qg) st[sub][r] = -1e30f;
            }
        }

        float tm = st[0][0];
#pragma unroll
        for (int r = 1; r < 16; ++r) tm = fmaxf(tm, st[0][r]);
#pragma unroll
        for (int r = 0; r < 16; ++r) tm = fmaxf(tm, st[1][r]);
        tm = fmaxf(tm, __shfl_xor(tm, 32));

        if (!__all(tm <= mrow + THR)) {  // defer-max (T13)
          float mn = fmaxf(mrow, tm);
          float al = __builtin_amdgcn_exp2f((mrow - mn) * c);
          mrow = mn;
          lrow *= al;
#pragma unroll
          for (int r = 0; r < 16; ++r) { y0[r] *= al; y1[r] *= al; }
        }

        const float mc = mrow * c;
        float ps = 0.f;
        unsigned pkw[2][8];
#pragma unroll
        for (int sub = 0; sub < 2; ++sub)
#pragma unroll
          for (int j = 0; j < 8; ++j) {
            float pa = __builtin_amdgcn_exp2f(fmaf(st[sub][2 * j], c, -mc));
            float pb = __builtin_amdgcn_exp2f(fmaf(st[sub][2 * j + 1], c, -mc));
            ps += pa + pb;
            pkw[sub][j] = pk2(pa, pb);
          }
        ps += __shfl_xor(ps, 32);
        lrow += ps;

        __builtin_amdgcn_s_setprio(1);
#pragma unroll
        for (int sub = 0; sub < 2; ++sub) {
#pragma unroll
          for (int ksl = 0; ksl < 2; ++ksl) {
            unsigned w0 = pkw[sub][ksl * 4 + 0], w2 = pkw[sub][ksl * 4 + 2];
            unsigned w1 = pkw[sub][ksl * 4 + 1], w3 = pkw[sub][ksl * 4 + 3];
            asm volatile("v_permlane32_swap_b32 %0, %1" : "+v"(w0), "+v"(w2));
            asm volatile("v_permlane32_swap_b32 %0, %1" : "+v"(w1), "+v"(w3));
            union { bf16x8 v; unsigned u[4]; } pf;
            pf.u[0] = w0; pf.u[1] = w1; pf.u[2] = w2; pf.u[3] = w3;
            const int cb = sub * 64 + ksl * 32 + hi * 16;
#pragma unroll
            for (int dm = 0; dm < 2; ++dm) {
              const int row = dm * 32 + q31;
              bf16x8 vf = *(const bf16x8*)((const unsigned char*)Vs[buf] +
                                           row * 128 + (cb ^ rswz));
              if (dm == 0) y0 = mfma32(vf, pf.v, y0);
              else         y1 = mfma32(vf, pf.v, y1);
            }
          }
        }
        __builtin_amdgcn_s_setprio(0);
      }

      // end-of-tile: my ds_reads done; counted wait (tile t+1 landed,
      // only tile t+2's 4 loads stay in flight); raw barrier (no drain)
      asm volatile("s_waitcnt lgkmcnt(0)" ::: "memory");
      __builtin_amdgcn_sched_barrier(0);
      if (t + 2 < NT) {
        asm volatile("s_waitcnt vmcnt(4)" ::: "memory");
      } else if (t + 1 < NT) {
        asm volatile("s_waitcnt vmcnt(0)" ::: "memory");
      }
      __builtin_amdgcn_sched_barrier(0);
      __builtin_amdgcn_s_barrier();
    }

    const int b = bh >> 4, h = bh & 15;
    float inv = __builtin_amdgcn_rcpf(lrow);
    unsigned short* yrow = Yb + (size_t)(b * 2048 + qg) * 1024 + h * 64;
#pragma unroll
    for (int dm = 0; dm < 2; ++dm)
#pragma unroll
      for (int g = 0; g < 4; ++g) {
        us4 o;
#pragma unroll
        for (int e = 0; e < 4; ++e) {
          float yv = dm ? y1[g * 4 + e] : y0[g * 4 + e];
          o[e] = f2bf_hw(yv * inv);
        }
        *(us4*)&yrow[dm * 32 + g * 8 + hi * 4] = o;
      }
  }
}

// ---------------------------------------------------------------- launch ----
extern "C" void kernel_launch(void* const* d_in, const int* in_sizes, int n_in,
                              void* d_out, int out_size, void* d_ws,
                              size_t ws_size, hipStream_t stream) {
  const float* x = (const float*)d_in[0];
  const float* Wa = (const float*)d_in[1];
  const float* Wp = (const float*)d_in[2];
  float* out = (float*)d_out;
  char* ws = (char*)d_ws;

  constexpr size_t OFF_WAT = 0;
  constexpr size_t OFF_WPT = 6291456;
  constexpr size_t OFF_COS = 8388608;
  constexpr size_t OFF_SIN = 8650752;
  constexpr size_t OFF_XB  = 8912896;
  constexpr size_t OFF_Q   = 25690112;
  constexpr size_t OFF_K   = 42467328;
  constexpr size_t OFF_V   = 59244544;

  unsigned short* WaT = (unsigned short*)(ws + OFF_WAT);
  unsigned short* WpT = (unsigned short*)(ws + OFF_WPT);
  float* cosT = (float*)(ws + OFF_COS);
  float* sinT = (float*)(ws + OFF_SIN);
  unsigned short* xb = (unsigned short*)(ws + OFF_XB);
  unsigned short* Yb = xb;
  unsigned short* Qr = (unsigned short*)(ws + OFF_Q);
  unsigned short* Kr = (unsigned short*)(ws + OFF_K);
  unsigned short* Vt = (unsigned short*)(ws + OFF_V);

  // 1) prep (merged)
  prep_kernel<<<2048 + 3072 + 1024 + 256, 256, 0, stream>>>(
      x, xb, Wa, WaT, Wp, WpT, cosT, sinT);

  // 2) qkv = x @ W_attn, fused RoPE + scatter (frozen GEMM; 768 wgs)
  gemm_bt_kernel<1><<<dim3(24, 32), 512, 0, stream>>>(
      xb, WaT, nullptr, 3072, 1024, cosT, sinT, Qr, Kr, Vt);

  // 3) causal flash attention -> Yb (ring-3 pipeline, 512 wgs, 3 blk/CU)
  attn_kernel<<<dim3(8, 64), 256, 0, stream>>>(Qr, Kr, Vt, Yb);

  // 4) out = y @ W_proj (frozen GEMM; 256 wgs = 1.0/CU)
  gemm_bt_kernel<0><<<dim3(8, 32), 512, 0, stream>>>(
      Yb, WpT, out, 1024, 1024, nullptr, nullptr, nullptr, nullptr, nullptr);
}